// Round 7
// baseline (253.897 us; speedup 1.0000x reference)
//
#include <hip/hip_runtime.h>
#include <hip/hip_cooperative_groups.h>
#include <math.h>

namespace coopg = cooperative_groups;

#define NN 256
#define FEAT 1024
#define HIDR 256
#define HEADS 4
#define GCNH 256
#define M1 1024            // HEADS*GCNH
#define OUTC 21
#define MAXDEG (NN + 1)    // up to 256 topk-incoming + 1 self loop
#define KC 16              // split-K factor for the fused GEMM
#define KCH (FEAT / KC)    // 64
#define RB 16              // rows per k_big block
#define FCOLS 1536         // fused output cols: A(256) | B(256) | hpre(1024)

// ---------------------------------------------------------------------------
// K1: fused split-K GEMM. Output cols [0,256)=A pre-bias, [256,512)=B,
// [512,1536)=feat@W1[:1024]. grid (16 row-groups of 16, 3 col-groups of 512,
// 16 K-chunks) = 768 blocks, block 256. 16-row tile doubles W-reuse vs the
// 8-row tile (R5 showed reuse >> occupancy here). Register double-buffer
// prefetch; one-group overshoot bounds: A-region reads Wfc1 rows <=1027
// (<2052), B-region <=2051 (=last), W1 <=1027 (<1028) — all in-bounds.
__global__ __launch_bounds__(256) void k_big(
        const float* __restrict__ feat, const float* __restrict__ Wfc1,
        const float* __restrict__ W1, float* __restrict__ P) {
    __shared__ float fS[RB][KCH];
    int rg = blockIdx.x, cgy = blockIdx.y, kc = blockIdx.z;
    int tid = threadIdx.x;
    int r0 = rg * RB, k0 = kc * KCH;
    for (int x = tid; x < RB * KCH; x += 256) {
        int r = x >> 6, kk = x & (KCH - 1);
        fS[r][kk] = feat[(size_t)(r0 + r) * FEAT + k0 + kk];
    }
    __syncthreads();
    int gc = cgy * 512 + tid * 2;
    const float* pW;
    int ld;
    if (gc < 256)      { pW = Wfc1 + (size_t)k0 * HIDR + gc;                  ld = HIDR; }
    else if (gc < 512) { pW = Wfc1 + (size_t)(FEAT + k0) * HIDR + (gc - 256); ld = HIDR; }
    else               { pW = W1   + (size_t)k0 * M1 + (gc - 512);            ld = M1;   }
    float2 acc[RB];
#pragma unroll
    for (int r = 0; r < RB; r++) { acc[r].x = 0.f; acc[r].y = 0.f; }
    float2 w0 = *(const float2*)(pW);
    float2 w1 = *(const float2*)(pW + ld);
    float2 w2 = *(const float2*)(pW + 2 * ld);
    float2 w3 = *(const float2*)(pW + 3 * ld);
    for (int kk = 0; kk < KCH; kk += 4) {
        pW += 4 * ld;
        float2 n0 = *(const float2*)(pW);
        float2 n1 = *(const float2*)(pW + ld);
        float2 n2 = *(const float2*)(pW + 2 * ld);
        float2 n3 = *(const float2*)(pW + 3 * ld);
#pragma unroll
        for (int r = 0; r < RB; r++) {
            float4 f = *(const float4*)&fS[r][kk];
            acc[r].x = fmaf(f.x, w0.x, acc[r].x); acc[r].y = fmaf(f.x, w0.y, acc[r].y);
            acc[r].x = fmaf(f.y, w1.x, acc[r].x); acc[r].y = fmaf(f.y, w1.y, acc[r].y);
            acc[r].x = fmaf(f.z, w2.x, acc[r].x); acc[r].y = fmaf(f.z, w2.y, acc[r].y);
            acc[r].x = fmaf(f.w, w3.x, acc[r].x); acc[r].y = fmaf(f.w, w3.y, acc[r].y);
        }
        w0 = n0; w1 = n1; w2 = n2; w3 = n3;
    }
    float* Pp = P + ((size_t)kc * NN + r0) * FCOLS + gc;
#pragma unroll
    for (int r = 0; r < RB; r++)
        *(float2*)(Pp + (size_t)r * FCOLS) = acc[r];
}

// ---------------------------------------------------------------------------
// K2: cooperative tail — everything after the big GEMM in one kernel.
// grid 256 (block b == row/target b), block 512, grid.sync() between phases.
//  A: reduce 16 split-K partials, route (A-row -> LDS only; BT4 packed
//     transpose; hpre + geom fixup + es1/ed1 dots).
//  B: rel row + top-3 (stable argmax rounds).
//  C: edge-list build + GAT-1 aggregate + h1@W2 + es2/ed2.
//  D: GAT-2 -> logits + argmax labels.
__global__ __launch_bounds__(512) void k_tail(
        const float* __restrict__ P, const float* __restrict__ bfc1,
        const float* __restrict__ boxes, const int* __restrict__ imh,
        const int* __restrict__ imw, const float* __restrict__ W1,
        const float* __restrict__ as1, const float* __restrict__ ad1,
        const float* __restrict__ Wfc1, const float* __restrict__ Wfc2,
        const float* __restrict__ b1, const float* __restrict__ W2,
        const float* __restrict__ as2, const float* __restrict__ ad2,
        const float* __restrict__ b2, float* __restrict__ BT4,
        float* __restrict__ hpre, float* __restrict__ es1,
        float* __restrict__ ed1, int* __restrict__ idxTop,
        int* __restrict__ deg, int* __restrict__ inlist,
        float* __restrict__ h2, float* __restrict__ es2,
        float* __restrict__ ed2, float* __restrict__ out) {
    coopg::grid_group grid = coopg::this_grid();
    __shared__ float gS[4];
    __shared__ float As[HIDR], w2s[HIDR];
    __shared__ float wg0[HIDR], wg1[HIDR], wg2[HIDR], wg3[HIDR];
    __shared__ float sval[512];
    __shared__ unsigned long long swk[8];
    __shared__ int win;
    __shared__ int pfxS[NN];
    __shared__ int lst[MAXDEG];
    __shared__ int dgS;
    __shared__ float sc[MAXDEG * 4];
    __shared__ float mh[4], dh[4];
    __shared__ float shh[M1];
    __shared__ float part[12 * OUTC];
    __shared__ float h2row[OUTC];
    __shared__ float sc2[MAXDEG];
    __shared__ float md[2];
    __shared__ float lv[OUTC];

    const int b = blockIdx.x;      // row / target node
    const int tid = threadIdx.x;

    // ---------------- Phase A: reduce + route ----------------
    if (tid == 0) {
        float w = (float)imw[0], h = (float)imh[0];
        float x1 = boxes[b * 4 + 0] / w, y1 = boxes[b * 4 + 1] / h;
        float x2 = boxes[b * 4 + 2] / w, y2 = boxes[b * 4 + 3] / h;
        gS[0] = x1; gS[1] = y1; gS[2] = x2 - x1; gS[3] = y2 - y1;
    }
    __syncthreads();
    if (tid < 384) {
        int c4 = tid * 4;
        const float* p = P + (size_t)b * FCOLS + c4;
        const size_t str = (size_t)NN * FCOLS;
        float4 a0 = *(const float4*)(p);
        float4 a1 = *(const float4*)(p + str);
        float4 a2 = *(const float4*)(p + 2 * str);
        float4 a3 = *(const float4*)(p + 3 * str);
#pragma unroll
        for (int q = 4; q < KC; q += 4) {
            float4 t0 = *(const float4*)(p + (size_t)q * str);
            float4 t1 = *(const float4*)(p + (size_t)(q + 1) * str);
            float4 t2 = *(const float4*)(p + (size_t)(q + 2) * str);
            float4 t3 = *(const float4*)(p + (size_t)(q + 3) * str);
            a0.x += t0.x; a0.y += t0.y; a0.z += t0.z; a0.w += t0.w;
            a1.x += t1.x; a1.y += t1.y; a1.z += t1.z; a1.w += t1.w;
            a2.x += t2.x; a2.y += t2.y; a2.z += t2.z; a2.w += t2.w;
            a3.x += t3.x; a3.y += t3.y; a3.z += t3.z; a3.w += t3.w;
        }
        float4 s;
        s.x = (a0.x + a1.x) + (a2.x + a3.x);
        s.y = (a0.y + a1.y) + (a2.y + a3.y);
        s.z = (a0.z + a1.z) + (a2.z + a3.z);
        s.w = (a0.w + a1.w) + (a2.w + a3.w);
        if (c4 < 256) {
            // A row b: needed only by THIS block's phase B -> LDS, no global
            float4 bb = *(const float4*)(bfc1 + c4);
            As[c4 + 0] = s.x + bb.x;
            As[c4 + 1] = s.y + bb.y;
            As[c4 + 2] = s.z + bb.z;
            As[c4 + 3] = s.w + bb.w;
        } else if (c4 < 512) {
            int kk = c4 - 256;   // kk % 4 == 0
            *(float4*)(BT4 + (size_t)(kk >> 2) * (NN * 4) + b * 4) = s;
        } else {
            int ch = c4 - 512;
            float g0 = gS[0], g1 = gS[1], g2 = gS[2], g3 = gS[3];
            float4 wv;
            wv = *(const float4*)(W1 + (size_t)(FEAT + 0) * M1 + ch);
            s.x = fmaf(g0, wv.x, s.x); s.y = fmaf(g0, wv.y, s.y);
            s.z = fmaf(g0, wv.z, s.z); s.w = fmaf(g0, wv.w, s.w);
            wv = *(const float4*)(W1 + (size_t)(FEAT + 1) * M1 + ch);
            s.x = fmaf(g1, wv.x, s.x); s.y = fmaf(g1, wv.y, s.y);
            s.z = fmaf(g1, wv.z, s.z); s.w = fmaf(g1, wv.w, s.w);
            wv = *(const float4*)(W1 + (size_t)(FEAT + 2) * M1 + ch);
            s.x = fmaf(g2, wv.x, s.x); s.y = fmaf(g2, wv.y, s.y);
            s.z = fmaf(g2, wv.z, s.z); s.w = fmaf(g2, wv.w, s.w);
            wv = *(const float4*)(W1 + (size_t)(FEAT + 3) * M1 + ch);
            s.x = fmaf(g3, wv.x, s.x); s.y = fmaf(g3, wv.y, s.y);
            s.z = fmaf(g3, wv.z, s.z); s.w = fmaf(g3, wv.w, s.w);
            *(float4*)(hpre + (size_t)b * M1 + ch) = s;
            float4 av = *(const float4*)(as1 + ch);
            float4 dv = *(const float4*)(ad1 + ch);
            float ps = s.x * av.x + s.y * av.y + s.z * av.z + s.w * av.w;
            float pd = s.x * dv.x + s.y * dv.y + s.z * dv.z + s.w * dv.w;
#pragma unroll
            for (int o = 32; o > 0; o >>= 1) {
                ps += __shfl_down(ps, o);
                pd += __shfl_down(pd, o);
            }
            if ((tid & 63) == 0) {
                int head = (tid - 128) >> 6;
                es1[b * 4 + head] = ps;
                ed1[b * 4 + head] = pd;
            }
        }
    }
    grid.sync();

    // ---------------- Phase B: rel row + top-3 ----------------
    {
        int j = tid & 255, half = tid >> 8;
        if (tid < 256) {
            w2s[tid] = Wfc2[tid];
            wg0[tid] = Wfc1[(size_t)(2 * FEAT + 0) * HIDR + tid];
        } else {
            int q = tid - 256;
            wg1[q] = Wfc1[(size_t)(2 * FEAT + 1) * HIDR + q];
            wg2[q] = Wfc1[(size_t)(2 * FEAT + 2) * HIDR + q];
            wg3[q] = Wfc1[(size_t)(2 * FEAT + 3) * HIDR + q];
        }
        float bi0 = boxes[b * 4 + 0], bi1 = boxes[b * 4 + 1];
        float bi2 = boxes[b * 4 + 2], bi3 = boxes[b * 4 + 3];
        float g0 = fabsf(bi0 - boxes[j * 4 + 0]);
        float g1 = fabsf(bi1 - boxes[j * 4 + 1]);
        float g2 = fabsf(bi2 - boxes[j * 4 + 2]);
        float g3 = fabsf(bi3 - boxes[j * 4 + 3]);
        __syncthreads();
        int k0 = half * 128;
        const float* pB = BT4 + (size_t)(k0 >> 2) * (NN * 4) + j * 4;
        float acc = 0.f;
        for (int kk = k0; kk < k0 + 128; kk += 4) {
            float4 a4 = *(const float4*)&As[kk];
            float4 w4 = *(const float4*)&w2s[kk];
            float4 q0 = *(const float4*)&wg0[kk];
            float4 q1 = *(const float4*)&wg1[kk];
            float4 q2 = *(const float4*)&wg2[kk];
            float4 q3 = *(const float4*)&wg3[kk];
            float4 b4 = *(const float4*)pB;
            pB += NN * 4;
            float v;
            v = a4.x + b4.x; v = fmaf(g0, q0.x, v); v = fmaf(g1, q1.x, v);
            v = fmaf(g2, q2.x, v); v = fmaf(g3, q3.x, v);
            acc = fmaf(fmaxf(v, 0.f), w4.x, acc);
            v = a4.y + b4.y; v = fmaf(g0, q0.y, v); v = fmaf(g1, q1.y, v);
            v = fmaf(g2, q2.y, v); v = fmaf(g3, q3.y, v);
            acc = fmaf(fmaxf(v, 0.f), w4.y, acc);
            v = a4.z + b4.z; v = fmaf(g0, q0.z, v); v = fmaf(g1, q1.z, v);
            v = fmaf(g2, q2.z, v); v = fmaf(g3, q3.z, v);
            acc = fmaf(fmaxf(v, 0.f), w4.z, acc);
            v = a4.w + b4.w; v = fmaf(g0, q0.w, v); v = fmaf(g1, q1.w, v);
            v = fmaf(g2, q2.w, v); v = fmaf(g3, q3.w, v);
            acc = fmaf(fmaxf(v, 0.f), w4.w, acc);
        }
        sval[tid] = acc;
        __syncthreads();
        if (tid < 256) sval[tid] = sval[tid] + sval[tid + 256];
        __syncthreads();
        for (int r = 0; r < 4; r++) {
            unsigned long long key = 0ULL;
            if (tid < 256) {
                unsigned u = __float_as_uint(sval[tid]);
                u = (u & 0x80000000u) ? ~u : (u | 0x80000000u);
                key = ((unsigned long long)u << 32) | (unsigned)(NN - 1 - tid);
            }
#pragma unroll
            for (int o = 32; o > 0; o >>= 1) {
                unsigned long long nk = __shfl_down(key, o);
                if (nk > key) key = nk;
            }
            if ((tid & 63) == 0) swk[tid >> 6] = key;
            __syncthreads();
            if (tid == 0) {
                unsigned long long m = swk[0];
#pragma unroll
                for (int q = 1; q < 8; q++) if (swk[q] > m) m = swk[q];
                int wj = NN - 1 - (int)(m & 0xFFFFFFFFu);
                win = wj;
                if (r > 0) idxTop[b * 3 + (r - 1)] = wj;
            }
            __syncthreads();
            if (tid == win) sval[tid] = -1e38f;
            __syncthreads();
        }
    }
    grid.sync();

    // ---------------- Phase C: build + GAT-1 + h2 ----------------
    {
        int f = 0;
        if (tid < NN) {
            f = (idxTop[tid * 3 + 0] == b) | (idxTop[tid * 3 + 1] == b)
              | (idxTop[tid * 3 + 2] == b);
            pfxS[tid] = f;
        }
        __syncthreads();
        for (int o = 1; o < NN; o <<= 1) {
            int add = (tid >= o && tid < NN) ? pfxS[tid - o] : 0;
            __syncthreads();
            if (tid < NN) pfxS[tid] += add;
            __syncthreads();
        }
        if (tid < NN && f) {
            lst[pfxS[tid] - 1] = tid;
            inlist[b * MAXDEG + (pfxS[tid] - 1)] = tid;
        }
        if (tid == NN - 1) {
            int d = pfxS[NN - 1];
            lst[d] = b;                   // GATConv self loop
            inlist[b * MAXDEG + d] = b;
            dgS = d + 1;
            deg[b] = d + 1;
        }
        __syncthreads();
        int dg = dgS;
        for (int p = tid; p < dg * 4; p += 512) {
            int e = p >> 2, h = p & 3;
            int s = lst[e];
            float v = es1[s * 4 + h] + ed1[b * 4 + h];
            sc[p] = v >= 0.f ? v : 0.2f * v;  // leaky_relu(0.2)
        }
        __syncthreads();
        if (tid < 4) {
            float m = -1e30f;
            for (int e = 0; e < dg; e++) m = fmaxf(m, sc[e * 4 + tid]);
            float s = 0.f;
            for (int e = 0; e < dg; e++) s += expf(sc[e * 4 + tid] - m);
            mh[tid] = m; dh[tid] = s;
        }
        __syncthreads();
        for (int p = tid; p < dg * 4; p += 512) {
            int h = p & 3;
            sc[p] = expf(sc[p] - mh[h]) / dh[h];  // alpha
        }
        __syncthreads();
        if (tid < 256) {
            float acc4[4] = {0.f, 0.f, 0.f, 0.f};
            for (int e = 0; e < dg; e++) {
                int s = lst[e];
                const float* hs = hpre + (size_t)s * M1;
#pragma unroll
                for (int q = 0; q < 4; q++)
                    acc4[q] = fmaf(sc[e * 4 + q], hs[q * GCNH + tid], acc4[q]);
            }
#pragma unroll
            for (int q = 0; q < 4; q++) {
                int c = q * GCNH + tid;
                shh[c] = fmaxf(acc4[q] + b1[c], 0.f);   // h1 row, LDS only
            }
        }
        __syncthreads();
        if (tid < 252) {
            int o = tid % OUTC, p = tid / OUTC;
            float a2 = 0.f;
            for (int d = p; d < M1; d += 12)
                a2 = fmaf(shh[d], W2[d * OUTC + o], a2);
            part[p * OUTC + o] = a2;
        }
        __syncthreads();
        if (tid < OUTC) {
            float s = 0.f;
            for (int p = 0; p < 12; p++) s += part[p * OUTC + tid];
            h2[b * OUTC + tid] = s;
            h2row[tid] = s;
        }
        __syncthreads();
        if (tid == 0) {
            float s = 0.f, dd = 0.f;
            for (int k = 0; k < OUTC; k++) {
                s = fmaf(h2row[k], as2[k], s);
                dd = fmaf(h2row[k], ad2[k], dd);
            }
            es2[b] = s; ed2[b] = dd;
        }
    }
    grid.sync();

    // ---------------- Phase D: GAT-2 -> logits + labels ----------------
    {
        int dg = deg[b];
        float edt = ed2[b];
        for (int p = tid; p < dg; p += 512) {
            int s = inlist[b * MAXDEG + p];
            float v = es2[s] + edt;
            sc2[p] = v >= 0.f ? v : 0.2f * v;
        }
        __syncthreads();
        if (tid == 0) {
            float m = -1e30f;
            for (int e = 0; e < dg; e++) m = fmaxf(m, sc2[e]);
            float s = 0.f;
            for (int e = 0; e < dg; e++) s += expf(sc2[e] - m);
            md[0] = m; md[1] = s;
        }
        __syncthreads();
        if (tid < OUTC) {
            float acc = 0.f;
            for (int e = 0; e < dg; e++) {
                int s = inlist[b * MAXDEG + e];
                float a = expf(sc2[e] - md[0]) / md[1];
                acc = fmaf(a, h2[s * OUTC + tid], acc);
            }
            float v = acc + b2[tid];
            out[b * OUTC + tid] = v;
            lv[tid] = v;
        }
        __syncthreads();
        if (tid == 0) {
            int best = 0;
            float bv = lv[0];
            for (int o = 1; o < OUTC; o++)
                if (lv[o] > bv) { bv = lv[o]; best = o; }  // first max wins
            out[NN * OUTC + b] = (float)best;
        }
    }
}

// ---------------------------------------------------------------------------
extern "C" void kernel_launch(void* const* d_in, const int* in_sizes, int n_in,
                              void* d_out, int out_size, void* d_ws,
                              size_t ws_size, hipStream_t stream) {
    const float* feat  = (const float*)d_in[0];
    const float* boxes = (const float*)d_in[1];
    const float* Wfc1  = (const float*)d_in[2];
    const float* bfc1  = (const float*)d_in[3];
    const float* Wfc2  = (const float*)d_in[4];
    const float* bfc2  = (const float*)d_in[5];   (void)bfc2;
    const float* W1    = (const float*)d_in[6];
    const float* as1   = (const float*)d_in[7];
    const float* ad1   = (const float*)d_in[8];
    const float* b1    = (const float*)d_in[9];
    const float* W2    = (const float*)d_in[10];
    const float* as2   = (const float*)d_in[11];
    const float* ad2   = (const float*)d_in[12];
    const float* b2    = (const float*)d_in[13];
    const int*   imh   = (const int*)d_in[14];
    const int*   imw   = (const int*)d_in[15];

    float* ws = (float*)d_ws;
    float* P     = ws;  ws += KC * NN * FCOLS;   // 6,291,456 floats (25 MB)
    float* BT4   = ws;  ws += NN * HIDR;
    float* hpre  = ws;  ws += NN * M1;
    float* es1   = ws;  ws += NN * 4;
    float* ed1   = ws;  ws += NN * 4;
    float* h2    = ws;  ws += NN * OUTC;
    float* es2   = ws;  ws += NN;
    float* ed2   = ws;  ws += NN;
    int* deg     = (int*)ws;
    int* inlist  = deg + NN;
    int* idxTop  = inlist + NN * MAXDEG;

    float* out = (float*)d_out;

    k_big<<<dim3(NN / RB, 3, KC), 256, 0, stream>>>(feat, Wfc1, W1, P);

    void* args[] = {
        (void*)&P,   (void*)&bfc1, (void*)&boxes, (void*)&imh, (void*)&imw,
        (void*)&W1,  (void*)&as1,  (void*)&ad1,   (void*)&Wfc1,
        (void*)&Wfc2,(void*)&b1,   (void*)&W2,    (void*)&as2, (void*)&ad2,
        (void*)&b2,  (void*)&BT4,  (void*)&hpre,  (void*)&es1, (void*)&ed1,
        (void*)&idxTop, (void*)&deg, (void*)&inlist,
        (void*)&h2,  (void*)&es2,  (void*)&ed2,   (void*)&out
    };
    hipLaunchCooperativeKernel(reinterpret_cast<void*>(k_tail),
                               dim3(NN), dim3(512), args, 0, stream);
}

// Round 8
// 162.064 us; speedup vs baseline: 1.5666x; 1.5666x over previous
//
#include <hip/hip_runtime.h>
#include <math.h>

#define NN 256
#define FEAT 1024
#define HIDR 256
#define HEADS 4
#define GCNH 256
#define M1 1024            // HEADS*GCNH
#define OUTC 21
#define MAXDEG (NN + 1)    // up to 256 topk-incoming + 1 self loop
#define KC 16              // split-K factor for the fused GEMM
#define KCH (FEAT / KC)    // 64
#define RB 16              // rows per k_big block
#define FCOLS 1536         // fused output cols: A(256) | B(256) | hpre(1024)

// ---------------------------------------------------------------------------
// K1: fused split-K GEMM. Output cols [0,256)=A pre-bias, [256,512)=B,
// [512,1536)=feat@W1[:1024]. grid (16 row-groups of 16, 3 col-groups of 512,
// 16 K-chunks) = 768 blocks, block 256. 16-row tile doubles W-reuse vs the
// 8-row tile (R5/R6 showed reuse >> occupancy here). Register double-buffer
// prefetch; one-group overshoot bounds: A-region reads Wfc1 rows <=1027
// (<2052), B-region <=2051 (=last), W1 <=1027 (<1028) — all in-bounds.
__global__ __launch_bounds__(256) void k_big(
        const float* __restrict__ feat, const float* __restrict__ Wfc1,
        const float* __restrict__ W1, float* __restrict__ P) {
    __shared__ float fS[RB][KCH];
    int rg = blockIdx.x, cgy = blockIdx.y, kc = blockIdx.z;
    int tid = threadIdx.x;
    int r0 = rg * RB, k0 = kc * KCH;
    for (int x = tid; x < RB * KCH; x += 256) {
        int r = x >> 6, kk = x & (KCH - 1);
        fS[r][kk] = feat[(size_t)(r0 + r) * FEAT + k0 + kk];
    }
    __syncthreads();
    int gc = cgy * 512 + tid * 2;
    const float* pW;
    int ld;
    if (gc < 256)      { pW = Wfc1 + (size_t)k0 * HIDR + gc;                  ld = HIDR; }
    else if (gc < 512) { pW = Wfc1 + (size_t)(FEAT + k0) * HIDR + (gc - 256); ld = HIDR; }
    else               { pW = W1   + (size_t)k0 * M1 + (gc - 512);            ld = M1;   }
    float2 acc[RB];
#pragma unroll
    for (int r = 0; r < RB; r++) { acc[r].x = 0.f; acc[r].y = 0.f; }
    float2 w0 = *(const float2*)(pW);
    float2 w1 = *(const float2*)(pW + ld);
    float2 w2 = *(const float2*)(pW + 2 * ld);
    float2 w3 = *(const float2*)(pW + 3 * ld);
    for (int kk = 0; kk < KCH; kk += 4) {
        pW += 4 * ld;
        float2 n0 = *(const float2*)(pW);
        float2 n1 = *(const float2*)(pW + ld);
        float2 n2 = *(const float2*)(pW + 2 * ld);
        float2 n3 = *(const float2*)(pW + 3 * ld);
#pragma unroll
        for (int r = 0; r < RB; r++) {
            float4 f = *(const float4*)&fS[r][kk];
            acc[r].x = fmaf(f.x, w0.x, acc[r].x); acc[r].y = fmaf(f.x, w0.y, acc[r].y);
            acc[r].x = fmaf(f.y, w1.x, acc[r].x); acc[r].y = fmaf(f.y, w1.y, acc[r].y);
            acc[r].x = fmaf(f.z, w2.x, acc[r].x); acc[r].y = fmaf(f.z, w2.y, acc[r].y);
            acc[r].x = fmaf(f.w, w3.x, acc[r].x); acc[r].y = fmaf(f.w, w3.y, acc[r].y);
        }
        w0 = n0; w1 = n1; w2 = n2; w3 = n3;
    }
    float* Pp = P + ((size_t)kc * NN + r0) * FCOLS + gc;
#pragma unroll
    for (int r = 0; r < RB; r++)
        *(float2*)(Pp + (size_t)r * FCOLS) = acc[r];
}

// ---------------------------------------------------------------------------
// K2: reduce 16 split-K partials + route + geom fixup + attention dots.
// grid 256 (row), block 384 (one float4 of the 1536 fused cols per thread).
// Wave 0 -> A (+bias); wave 1 -> BT4 (packed transpose, float4 store);
// waves 2..5 -> hpre: add geom rows of W1, store, shuffle-reduce es1/ed1.
__global__ __launch_bounds__(384) void k_redfix(
        const float* __restrict__ P, const float* __restrict__ bfc1,
        const float* __restrict__ boxes, const int* __restrict__ imh,
        const int* __restrict__ imw, const float* __restrict__ W1,
        const float* __restrict__ as1, const float* __restrict__ ad1,
        float* __restrict__ A, float* __restrict__ BT4,
        float* __restrict__ hpre, float* __restrict__ es1,
        float* __restrict__ ed1, float* __restrict__ geomn) {
    __shared__ float gS[4];
    int row = blockIdx.x, tid = threadIdx.x;
    int c4 = tid * 4;
    const float* p = P + (size_t)row * FCOLS + c4;
    const size_t str = (size_t)NN * FCOLS;
    float4 a0 = *(const float4*)(p);
    float4 a1 = *(const float4*)(p + str);
    float4 a2 = *(const float4*)(p + 2 * str);
    float4 a3 = *(const float4*)(p + 3 * str);
#pragma unroll
    for (int q = 4; q < KC; q += 4) {
        float4 t0 = *(const float4*)(p + (size_t)q * str);
        float4 t1 = *(const float4*)(p + (size_t)(q + 1) * str);
        float4 t2 = *(const float4*)(p + (size_t)(q + 2) * str);
        float4 t3 = *(const float4*)(p + (size_t)(q + 3) * str);
        a0.x += t0.x; a0.y += t0.y; a0.z += t0.z; a0.w += t0.w;
        a1.x += t1.x; a1.y += t1.y; a1.z += t1.z; a1.w += t1.w;
        a2.x += t2.x; a2.y += t2.y; a2.z += t2.z; a2.w += t2.w;
        a3.x += t3.x; a3.y += t3.y; a3.z += t3.z; a3.w += t3.w;
    }
    float4 s;
    s.x = (a0.x + a1.x) + (a2.x + a3.x);
    s.y = (a0.y + a1.y) + (a2.y + a3.y);
    s.z = (a0.z + a1.z) + (a2.z + a3.z);
    s.w = (a0.w + a1.w) + (a2.w + a3.w);
    if (tid == 0) {
        float w = (float)imw[0], h = (float)imh[0];
        float x1 = boxes[row * 4 + 0] / w, y1 = boxes[row * 4 + 1] / h;
        float x2 = boxes[row * 4 + 2] / w, y2 = boxes[row * 4 + 3] / h;
        gS[0] = x1; gS[1] = y1; gS[2] = x2 - x1; gS[3] = y2 - y1;
        geomn[row * 4 + 0] = x1;
        geomn[row * 4 + 1] = y1;
        geomn[row * 4 + 2] = x2 - x1;
        geomn[row * 4 + 3] = y2 - y1;
    }
    __syncthreads();
    if (c4 < 256) {
        float4 b = *(const float4*)(bfc1 + c4);
        s.x += b.x; s.y += b.y; s.z += b.z; s.w += b.w;
        *(float4*)(A + (size_t)row * HIDR + c4) = s;
    } else if (c4 < 512) {
        int kk = c4 - 256;   // kk % 4 == 0
        // packed transpose: one float4 store of k-values kk..kk+3 for col=row
        *(float4*)(BT4 + (size_t)(kk >> 2) * (NN * 4) + row * 4) = s;
    } else {
        int ch = c4 - 512;
        float g0 = gS[0], g1 = gS[1], g2 = gS[2], g3 = gS[3];
        float4 wv;
        wv = *(const float4*)(W1 + (size_t)(FEAT + 0) * M1 + ch);
        s.x = fmaf(g0, wv.x, s.x); s.y = fmaf(g0, wv.y, s.y);
        s.z = fmaf(g0, wv.z, s.z); s.w = fmaf(g0, wv.w, s.w);
        wv = *(const float4*)(W1 + (size_t)(FEAT + 1) * M1 + ch);
        s.x = fmaf(g1, wv.x, s.x); s.y = fmaf(g1, wv.y, s.y);
        s.z = fmaf(g1, wv.z, s.z); s.w = fmaf(g1, wv.w, s.w);
        wv = *(const float4*)(W1 + (size_t)(FEAT + 2) * M1 + ch);
        s.x = fmaf(g2, wv.x, s.x); s.y = fmaf(g2, wv.y, s.y);
        s.z = fmaf(g2, wv.z, s.z); s.w = fmaf(g2, wv.w, s.w);
        wv = *(const float4*)(W1 + (size_t)(FEAT + 3) * M1 + ch);
        s.x = fmaf(g3, wv.x, s.x); s.y = fmaf(g3, wv.y, s.y);
        s.z = fmaf(g3, wv.z, s.z); s.w = fmaf(g3, wv.w, s.w);
        *(float4*)(hpre + (size_t)row * M1 + ch) = s;
        float4 a = *(const float4*)(as1 + ch);
        float4 b = *(const float4*)(ad1 + ch);
        float ps = s.x * a.x + s.y * a.y + s.z * a.z + s.w * a.w;
        float pd = s.x * b.x + s.y * b.y + s.z * b.z + s.w * b.w;
#pragma unroll
        for (int o = 32; o > 0; o >>= 1) {
            ps += __shfl_down(ps, o);
            pd += __shfl_down(pd, o);
        }
        if ((tid & 63) == 0) {
            int head = (tid - 128) >> 6;
            es1[row * 4 + head] = ps;
            ed1[row * 4 + head] = pd;
        }
    }
}

// ---------------------------------------------------------------------------
// K3: fused rel-row + top-k. grid 256 (row i), block 512: thread (j, half)
// computes the K-half of rel[i][j] = sum_k relu(A[i,k]+B[k,j]+g.Wg[:,k])
// *W_fc2[k] using the packed BT4 layout (one float4 = 4 k-values per load);
// halves combined in LDS; then 4 rounds of block argmax on packed key
// (orderedFloat<<32 | (255-j)) -> rank 1..3 indices (jax.lax.top_k stable
// order). rel never hits global. (b_fc2 dropped: constant shift.)
__global__ __launch_bounds__(512) void k_reltopk(
        const float* __restrict__ A, const float* __restrict__ BT4,
        const float* __restrict__ boxes, const float* __restrict__ Wfc1,
        const float* __restrict__ Wfc2, int* __restrict__ idxTop) {
    __shared__ float As[HIDR], w2s[HIDR], wg0[HIDR], wg1[HIDR], wg2[HIDR], wg3[HIDR];
    __shared__ float sval[512];
    __shared__ unsigned long long swk[8];
    __shared__ int win;
    int i = blockIdx.x, tid = threadIdx.x;
    int j = tid & 255, half = tid >> 8;
    if (tid < 256) {
        As[tid]  = A[i * HIDR + tid];
        w2s[tid] = Wfc2[tid];
        wg0[tid] = Wfc1[(size_t)(2 * FEAT + 0) * HIDR + tid];
    } else {
        int q = tid - 256;
        wg1[q] = Wfc1[(size_t)(2 * FEAT + 1) * HIDR + q];
        wg2[q] = Wfc1[(size_t)(2 * FEAT + 2) * HIDR + q];
        wg3[q] = Wfc1[(size_t)(2 * FEAT + 3) * HIDR + q];
    }
    float bi0 = boxes[i * 4 + 0], bi1 = boxes[i * 4 + 1];
    float bi2 = boxes[i * 4 + 2], bi3 = boxes[i * 4 + 3];
    float g0 = fabsf(bi0 - boxes[j * 4 + 0]);
    float g1 = fabsf(bi1 - boxes[j * 4 + 1]);
    float g2 = fabsf(bi2 - boxes[j * 4 + 2]);
    float g3 = fabsf(bi3 - boxes[j * 4 + 3]);
    __syncthreads();
    int k0 = half * 128;
    const float* pB = BT4 + (size_t)(k0 >> 2) * (NN * 4) + j * 4;
    float acc = 0.f;
    for (int kk = k0; kk < k0 + 128; kk += 4) {
        float4 a4 = *(const float4*)&As[kk];
        float4 w4 = *(const float4*)&w2s[kk];
        float4 q0 = *(const float4*)&wg0[kk];
        float4 q1 = *(const float4*)&wg1[kk];
        float4 q2 = *(const float4*)&wg2[kk];
        float4 q3 = *(const float4*)&wg3[kk];
        float4 b4 = *(const float4*)pB;
        pB += NN * 4;
        float v;
        v = a4.x + b4.x; v = fmaf(g0, q0.x, v); v = fmaf(g1, q1.x, v);
        v = fmaf(g2, q2.x, v); v = fmaf(g3, q3.x, v);
        acc = fmaf(fmaxf(v, 0.f), w4.x, acc);
        v = a4.y + b4.y; v = fmaf(g0, q0.y, v); v = fmaf(g1, q1.y, v);
        v = fmaf(g2, q2.y, v); v = fmaf(g3, q3.y, v);
        acc = fmaf(fmaxf(v, 0.f), w4.y, acc);
        v = a4.z + b4.z; v = fmaf(g0, q0.z, v); v = fmaf(g1, q1.z, v);
        v = fmaf(g2, q2.z, v); v = fmaf(g3, q3.z, v);
        acc = fmaf(fmaxf(v, 0.f), w4.z, acc);
        v = a4.w + b4.w; v = fmaf(g0, q0.w, v); v = fmaf(g1, q1.w, v);
        v = fmaf(g2, q2.w, v); v = fmaf(g3, q3.w, v);
        acc = fmaf(fmaxf(v, 0.f), w4.w, acc);
    }
    sval[tid] = acc;
    __syncthreads();
    if (tid < 256) sval[tid] = sval[tid] + sval[tid + 256];
    __syncthreads();
    for (int r = 0; r < 4; r++) {
        unsigned long long key = 0ULL;
        if (tid < 256) {
            unsigned u = __float_as_uint(sval[tid]);
            u = (u & 0x80000000u) ? ~u : (u | 0x80000000u);
            key = ((unsigned long long)u << 32) | (unsigned)(NN - 1 - tid);
        }
#pragma unroll
        for (int o = 32; o > 0; o >>= 1) {
            unsigned long long nk = __shfl_down(key, o);
            if (nk > key) key = nk;
        }
        if ((tid & 63) == 0) swk[tid >> 6] = key;
        __syncthreads();
        if (tid == 0) {
            unsigned long long m = swk[0];
#pragma unroll
            for (int q = 1; q < 8; q++) if (swk[q] > m) m = swk[q];
            int wj = NN - 1 - (int)(m & 0xFFFFFFFFu);
            win = wj;
            if (r > 0) idxTop[i * 3 + (r - 1)] = wj;
        }
        __syncthreads();
        if (tid == win) sval[tid] = -1e38f;
        __syncthreads();
    }
}

// ---------------------------------------------------------------------------
// K4: fused edge-list build + GAT-1 aggregate (+bias+relu, h1 in LDS) +
// h2 = h1@W2 (1024->21) + es2/ed2 dots. grid 256 (target t), block 256.
__global__ __launch_bounds__(256) void k_gat1h2(
        const float* __restrict__ idxTopF, const float* __restrict__ hpre,
        const float* __restrict__ es1, const float* __restrict__ ed1,
        const float* __restrict__ b1, const float* __restrict__ W2,
        const float* __restrict__ as2, const float* __restrict__ ad2,
        int* __restrict__ deg, int* __restrict__ inlist,
        float* __restrict__ h2, float* __restrict__ es2,
        float* __restrict__ ed2) {
    const int* idxTop = (const int*)idxTopF;
    __shared__ int pfx[NN];
    __shared__ int lst[MAXDEG];
    __shared__ int dgS;
    __shared__ float sc[MAXDEG * 4];
    __shared__ float mh[4], dh[4];
    __shared__ float sh[M1];
    __shared__ float part[12 * OUTC];
    __shared__ float h2row[OUTC];
    int t = blockIdx.x, tid = threadIdx.x;
    // --- build incoming edge list for target t (ascending sources) ---
    int f = (idxTop[tid * 3 + 0] == t) | (idxTop[tid * 3 + 1] == t)
          | (idxTop[tid * 3 + 2] == t);
    pfx[tid] = f;
    __syncthreads();
    for (int o = 1; o < NN; o <<= 1) {
        int add = (tid >= o) ? pfx[tid - o] : 0;
        __syncthreads();
        pfx[tid] += add;
        __syncthreads();
    }
    if (f) {
        lst[pfx[tid] - 1] = tid;
        inlist[t * MAXDEG + (pfx[tid] - 1)] = tid;
    }
    if (tid == NN - 1) {
        int d = pfx[NN - 1];
        lst[d] = t;                       // GATConv self loop
        inlist[t * MAXDEG + d] = t;
        dgS = d + 1;
        deg[t] = d + 1;
    }
    __syncthreads();
    int dg = dgS;
    // --- attention scores + softmax over incoming edges ---
    for (int p = tid; p < dg * 4; p += 256) {
        int e = p >> 2, h = p & 3;
        int s = lst[e];
        float v = es1[s * 4 + h] + ed1[t * 4 + h];
        sc[p] = v >= 0.f ? v : 0.2f * v;  // leaky_relu(0.2)
    }
    __syncthreads();
    if (tid < 4) {
        float m = -1e30f;
        for (int e = 0; e < dg; e++) m = fmaxf(m, sc[e * 4 + tid]);
        float s = 0.f;
        for (int e = 0; e < dg; e++) s += expf(sc[e * 4 + tid] - m);
        mh[tid] = m; dh[tid] = s;
    }
    __syncthreads();
    for (int p = tid; p < dg * 4; p += 256) {
        int h = p & 3;
        sc[p] = expf(sc[p] - mh[h]) / dh[h];  // alpha
    }
    __syncthreads();
    // --- aggregate ---
    float acc[4] = {0.f, 0.f, 0.f, 0.f};
    for (int e = 0; e < dg; e++) {
        int s = lst[e];
        const float* hs = hpre + (size_t)s * M1;
#pragma unroll
        for (int q = 0; q < 4; q++)
            acc[q] = fmaf(sc[e * 4 + q], hs[q * GCNH + tid], acc[q]);
    }
#pragma unroll
    for (int q = 0; q < 4; q++) {
        int c = q * GCNH + tid;
        sh[c] = fmaxf(acc[q] + b1[c], 0.f);   // h1 row, LDS only
    }
    __syncthreads();
    // --- h2 projection (1024 -> 21) ---
    if (tid < 252) {
        int o = tid % OUTC, p = tid / OUTC;
        float a2 = 0.f;
        for (int d = p; d < M1; d += 12)
            a2 = fmaf(sh[d], W2[d * OUTC + o], a2);
        part[p * OUTC + o] = a2;
    }
    __syncthreads();
    if (tid < OUTC) {
        float s = 0.f;
        for (int p = 0; p < 12; p++) s += part[p * OUTC + tid];
        h2[t * OUTC + tid] = s;
        h2row[tid] = s;
    }
    __syncthreads();
    if (tid == 0) {
        float s = 0.f, dd = 0.f;
        for (int k = 0; k < OUTC; k++) {
            s = fmaf(h2row[k], as2[k], s);
            dd = fmaf(h2row[k], ad2[k], dd);
        }
        es2[t] = s; ed2[t] = dd;
    }
}

// ---------------------------------------------------------------------------
// K5: GAT layer 2 softmax-aggregate + bias -> logits; argmax -> labels.
// grid 256 (target t), block 64. out = [logits (256x21) | labels (256) as f32]
__global__ __launch_bounds__(64) void k_gat2(
        const float* __restrict__ h2, const float* __restrict__ es2,
        const float* __restrict__ ed2, const int* __restrict__ deg,
        const int* __restrict__ inlist, const float* __restrict__ b2,
        float* __restrict__ out) {
    __shared__ float sc[MAXDEG];
    __shared__ float md[2];
    __shared__ float lv[OUTC];
    int t = blockIdx.x, tid = threadIdx.x;
    int dg = deg[t];
    float edt = ed2[t];
    for (int p = tid; p < dg; p += 64) {
        int s = inlist[t * MAXDEG + p];
        float v = es2[s] + edt;
        sc[p] = v >= 0.f ? v : 0.2f * v;
    }
    __syncthreads();
    if (tid == 0) {
        float m = -1e30f;
        for (int e = 0; e < dg; e++) m = fmaxf(m, sc[e]);
        float s = 0.f;
        for (int e = 0; e < dg; e++) s += expf(sc[e] - m);
        md[0] = m; md[1] = s;
    }
    __syncthreads();
    if (tid < OUTC) {
        float acc = 0.f;
        for (int e = 0; e < dg; e++) {
            int s = inlist[t * MAXDEG + e];
            float a = expf(sc[e] - md[0]) / md[1];
            acc = fmaf(a, h2[s * OUTC + tid], acc);
        }
        float v = acc + b2[tid];
        out[t * OUTC + tid] = v;
        lv[tid] = v;
    }
    __syncthreads();
    if (tid == 0) {
        int best = 0;
        float bv = lv[0];
        for (int o = 1; o < OUTC; o++)
            if (lv[o] > bv) { bv = lv[o]; best = o; }  // first max wins
        out[NN * OUTC + t] = (float)best;
    }
}

// ---------------------------------------------------------------------------
extern "C" void kernel_launch(void* const* d_in, const int* in_sizes, int n_in,
                              void* d_out, int out_size, void* d_ws,
                              size_t ws_size, hipStream_t stream) {
    const float* feat  = (const float*)d_in[0];
    const float* boxes = (const float*)d_in[1];
    const float* Wfc1  = (const float*)d_in[2];
    const float* bfc1  = (const float*)d_in[3];
    const float* Wfc2  = (const float*)d_in[4];
    const float* bfc2  = (const float*)d_in[5];   (void)bfc2;
    const float* W1    = (const float*)d_in[6];
    const float* as1   = (const float*)d_in[7];
    const float* ad1   = (const float*)d_in[8];
    const float* b1    = (const float*)d_in[9];
    const float* W2    = (const float*)d_in[10];
    const float* as2   = (const float*)d_in[11];
    const float* ad2   = (const float*)d_in[12];
    const float* b2    = (const float*)d_in[13];
    const int*   imh   = (const int*)d_in[14];
    const int*   imw   = (const int*)d_in[15];

    float* ws = (float*)d_ws;
    float* P     = ws;  ws += KC * NN * FCOLS;   // 6,291,456 floats (25 MB)
    float* A     = ws;  ws += NN * HIDR;
    float* BT4   = ws;  ws += NN * HIDR;
    float* hpre  = ws;  ws += NN * M1;
    float* es1   = ws;  ws += NN * 4;
    float* ed1   = ws;  ws += NN * 4;
    float* h2    = ws;  ws += NN * OUTC;
    float* es2   = ws;  ws += NN;
    float* ed2   = ws;  ws += NN;
    float* geomn = ws;  ws += NN * 4;
    int* deg     = (int*)ws;
    int* inlist  = deg + NN;
    int* idxTop  = inlist + NN * MAXDEG;

    float* out = (float*)d_out;

    k_big<<<dim3(NN / RB, 3, KC), 256, 0, stream>>>(feat, Wfc1, W1, P);
    k_redfix<<<NN, 384, 0, stream>>>(P, bfc1, boxes, imh, imw, W1, as1, ad1,
                                     A, BT4, hpre, es1, ed1, geomn);
    k_reltopk<<<NN, 512, 0, stream>>>(A, BT4, boxes, Wfc1, Wfc2, idxTop);
    k_gat1h2<<<NN, 256, 0, stream>>>((const float*)idxTop, hpre, es1, ed1,
                                     b1, W2, as2, ad2, deg, inlist,
                                     h2, es2, ed2);
    k_gat2<<<NN, 64, 0, stream>>>(h2, es2, ed2, deg, inlist, b2, out);
}